// Round 4
// baseline (584.329 us; speedup 1.0000x reference)
//
#include <hip/hip_runtime.h>
#include <cfloat>
#include <climits>

#define EOS_ID 1
#define NEXT_LINE_ID 2
#define IGNORE_IDX 0

constexpr int THREADS = 256;
constexpr float LOG2E = 1.4426950408889634f;

typedef float vf4 __attribute__((ext_vector_type(4)));

// ---------------------------------------------------------------------------
// Fused kernel: one block per (b,s) row of V logits.
// Phase 1 (all blocks): chunked online softmax (16 elems/iter via 4 coalesced
//   float4 loads, chunk-max tree + single deferred rescale, first-index
//   argmax), write per-row nll + argmax.
// Phase 2 (last-finishing block only, rocPRIM-style release/acquire via
//   device-scope atomic counter): CE mean + first-EOS / NEXT_LINE scans on
//   L2-hot nll/am + final scalar. Deterministic: fixed reduction orders,
//   finalize reads fixed data regardless of which block runs it.
// ---------------------------------------------------------------------------
__global__ __launch_bounds__(THREADS) void fused_ce_kernel(
    const float* __restrict__ pred, const int* __restrict__ target,
    float* __restrict__ nll_out, int* __restrict__ am_out,
    unsigned* __restrict__ counter, float* __restrict__ out,
    int V, int B, int S)
{
    const int row = blockIdx.x;
    const float* rp = pred + (size_t)row * (size_t)V;
    const int tid = threadIdx.x;
    const int V4 = V >> 2;          // float4 count (8000)
    const int SEG = V4 >> 2;        // float4 per segment (2000), 4 segments
    const int SEG4 = SEG << 2;      // elements per segment (8000)

    const int t = target[row];
    float xt = 0.0f;
    if (tid == 0) xt = rp[t];       // issue early; consumed after the loop

    const vf4* rp4 = (const vf4*)rp;

    float m = -FLT_MAX;
    float s = 0.0f;
    int bi = 0;

    for (int i = tid; i < SEG; i += THREADS) {
        vf4 v0 = __builtin_nontemporal_load(rp4 + i);
        vf4 v1 = __builtin_nontemporal_load(rp4 + i + SEG);
        vf4 v2 = __builtin_nontemporal_load(rp4 + i + 2 * SEG);
        vf4 v3 = __builtin_nontemporal_load(rp4 + i + 3 * SEG);
        float x[16];
#pragma unroll
        for (int c = 0; c < 4; ++c) {
            x[c] = v0[c]; x[4 + c] = v1[c]; x[8 + c] = v2[c]; x[12 + c] = v3[c];
        }
        // chunk max (tree, ILP)
        float m8[8];
#pragma unroll
        for (int j = 0; j < 8; ++j) m8[j] = fmaxf(x[2 * j], x[2 * j + 1]);
        float m4[4];
#pragma unroll
        for (int j = 0; j < 4; ++j) m4[j] = fmaxf(m8[2 * j], m8[2 * j + 1]);
        float mc = fmaxf(fmaxf(m4[0], m4[1]), fmaxf(m4[2], m4[3]));

        // earliest-index element offset of mc within the chunk.
        // slot j holds element (i<<2) + (j>>2)*SEG4 + (j&3); slot order is
        // increasing global index, so scanning j=14..0 keeps the earliest.
        int off = 3 * SEG4 + 3;
#pragma unroll
        for (int j = 14; j >= 0; --j)
            off = (x[j] == mc) ? ((j >> 2) * SEG4 + (j & 3)) : off;
        if (mc > m) bi = (i << 2) + off;   // strict > keeps earliest across chunks

        // deferred-rescale exp sum (all exps independent)
        float nm = fmaxf(m, mc);
        float nms = -nm * LOG2E;
        float r = exp2f(__builtin_fmaf(m, LOG2E, nms)); // m=-FLT_MAX -> 0
#pragma unroll
        for (int j = 0; j < 16; ++j)
            x[j] = exp2f(__builtin_fmaf(x[j], LOG2E, nms));
#pragma unroll
        for (int j = 0; j < 8; ++j) x[j] += x[j + 8];
#pragma unroll
        for (int j = 0; j < 4; ++j) x[j] += x[j + 4];
        float cs = (x[0] + x[1]) + (x[2] + x[3]);
        s = __builtin_fmaf(s, r, cs);
        m = nm;
    }

    // generic scalar tail (empty for V % 16 == 0)
    for (int i = (SEG << 4) + tid; i < V; i += THREADS) {
        float xv = rp[i];
        float nm = fmaxf(m, xv);
        float nms = -nm * LOG2E;
        s = s * exp2f(__builtin_fmaf(m, LOG2E, nms))
          + exp2f(__builtin_fmaf(xv, LOG2E, nms));
        if (xv > m) bi = i;
        m = nm;
    }

    // wave64 reduction
#pragma unroll
    for (int off = 32; off > 0; off >>= 1) {
        float m2 = __shfl_down(m, off);
        float s2 = __shfl_down(s, off);
        int bi2 = __shfl_down(bi, off);
        float nm = fmaxf(m, m2);
        float nms = -nm * LOG2E;
        s = s * exp2f(__builtin_fmaf(m, LOG2E, nms))
          + s2 * exp2f(__builtin_fmaf(m2, LOG2E, nms));
        bool take = (m2 > m) || (m2 == m && bi2 < bi);
        bi = take ? bi2 : bi;
        m = nm;
    }

    __shared__ float sm[THREADS / 64], ss[THREADS / 64];
    __shared__ int sbi[THREADS / 64];
    const int wave = tid >> 6;
    const int lane = tid & 63;
    if (lane == 0) { sm[wave] = m; ss[wave] = s; sbi[wave] = bi; }
    __syncthreads();

    if (tid == 0) {
#pragma unroll
        for (int w = 1; w < THREADS / 64; ++w) {
            float m2 = sm[w], s2 = ss[w];
            int bi2 = sbi[w];
            float nm = fmaxf(m, m2);
            float nms = -nm * LOG2E;
            s = s * exp2f(__builtin_fmaf(m, LOG2E, nms))
              + s2 * exp2f(__builtin_fmaf(m2, LOG2E, nms));
            bool take = (m2 > m) || (m2 == m && bi2 < bi);
            bi = take ? bi2 : bi;
            m = nm;
        }
        const float nll = logf(s) + m - xt;   // -log_softmax[target]
        nll_out[row] = (t != IGNORE_IDX) ? nll : 0.0f;
        am_out[row] = bi;
    }

    // ---- release: make this block's nll/am visible, count completion ----
    __shared__ int is_last;
    if (tid == 0) {
        __threadfence();
        unsigned prev = atomicAdd(counter, 1u);
        is_last = (prev == (unsigned)(gridDim.x - 1));
    }
    __syncthreads();
    if (!is_last) return;
    __threadfence();   // acquire: invalidate L1 before reading other blocks' data

    // =================== finalize (last block, 256 threads) ===================
    __shared__ float sfce[THREADS / 64];
    __shared__ int svc[THREADS / 64];
    __shared__ int sfirst[8], scount[8];
    const int BS = B * S;

    // CE numerator + valid count (vectorized, deterministic order)
    float ces = 0.0f;
    int vc = 0;
    const float4* nll4 = (const float4*)nll_out;
    const int4* tg4 = (const int4*)target;
    const int NV = BS >> 2;
    for (int i = tid; i < NV; i += THREADS) {
        float4 v = nll4[i];
        ces += (v.x + v.y) + (v.z + v.w);
        int4 tv = tg4[i];
        vc += (tv.x != IGNORE_IDX) + (tv.y != IGNORE_IDX)
            + (tv.z != IGNORE_IDX) + (tv.w != IGNORE_IDX);
    }
#pragma unroll
    for (int off = 32; off > 0; off >>= 1) {
        ces += __shfl_down(ces, off);
        vc += __shfl_down(vc, off);
    }
    if (lane == 0) { sfce[wave] = ces; svc[wave] = vc; }

    // scans: 8 tasks (4 rows x {argmax,target}) over 4 waves, 2 tasks/wave
    for (int task = wave; task < 2 * B; task += THREADS / 64) {
        const int r = task >> 1;
        const int* ids = (task & 1) ? (target + r * S) : (am_out + r * S);
        const int4* id4 = (const int4*)ids;
        const int S4 = S >> 2;

        int lmin = INT_MAX;
        for (int i = lane; i < S4; i += 64) {
            int4 v = id4[i];
            const int base = i << 2;
            int idx = INT_MAX;
            if (v.w == EOS_ID) idx = base + 3;
            if (v.z == EOS_ID) idx = base + 2;
            if (v.y == EOS_ID) idx = base + 1;
            if (v.x == EOS_ID) idx = base;
            lmin = min(lmin, idx);
        }
#pragma unroll
        for (int off = 32; off > 0; off >>= 1)
            lmin = min(lmin, __shfl_down(lmin, off));
        lmin = __shfl(lmin, 0);
        const int first = min(lmin, S - 1);

        int c = 0;
        for (int i = lane; i < S4; i += 64) {
            int4 v = id4[i];                    // L1-hot second pass
            const int base = i << 2;
            c += (v.x == NEXT_LINE_ID && base <= first);
            c += (v.y == NEXT_LINE_ID && base + 1 <= first);
            c += (v.z == NEXT_LINE_ID && base + 2 <= first);
            c += (v.w == NEXT_LINE_ID && base + 3 <= first);
        }
#pragma unroll
        for (int off = 32; off > 0; off >>= 1)
            c += __shfl_down(c, off);
        if (lane == 0) { sfirst[task] = first; scount[task] = c; }
    }
    __syncthreads();

    if (tid == 0) {
        float ce_total = 0.0f;
        int vtot = 0;
#pragma unroll
        for (int w = 0; w < THREADS / 64; ++w) { ce_total += sfce[w]; vtot += svc[w]; }
        int SL = 0, SC = 0;
#pragma unroll
        for (int b = 0; b < 4; ++b) {
            SL += abs(sfirst[2 * b] - sfirst[2 * b + 1]);
            SC += abs(scount[2 * b] - scount[2 * b + 1]);
        }
        float ce = ce_total / fmaxf((float)vtot, 1.0f);
        out[0] = 0.98f * ce + 0.01f * ((float)SL / (float)B)
                            + 0.01f * ((float)SC / (float)B);
    }
}

extern "C" void kernel_launch(void* const* d_in, const int* in_sizes, int n_in,
                              void* d_out, int out_size, void* d_ws, size_t ws_size,
                              hipStream_t stream)
{
    const float* pred = (const float*)d_in[0];
    const int* target = (const int*)d_in[1];
    float* out = (float*)d_out;

    const int rows = in_sizes[1];                         // B*S = 8192
    const int V = (int)((long long)in_sizes[0] / rows);   // 32000
    const int B = 4;
    const int S = rows / B;                               // 2048

    float* nll = (float*)d_ws;
    int* am = (int*)(nll + rows);
    unsigned* counter = (unsigned*)(am + rows);

    // counter must be 0 at every call (ws is poisoned once, never re-poisoned)
    hipMemsetAsync(counter, 0, sizeof(unsigned), stream);

    fused_ce_kernel<<<rows, THREADS, 0, stream>>>(pred, target, nll, am,
                                                  counter, out, V, B, S);
}

// Round 5
// 582.398 us; speedup vs baseline: 1.0033x; 1.0033x over previous
//
#include <hip/hip_runtime.h>
#include <cfloat>
#include <climits>

#define EOS_ID 1
#define NEXT_LINE_ID 2
#define IGNORE_IDX 0

constexpr int THREADS = 256;
constexpr float LOG2E = 1.4426950408889634f;

typedef float vf4 __attribute__((ext_vector_type(4)));

// Tiny init kernel: zero the completion counter. A rocclr memset node in the
// captured graph costs ~400+ us per replay (R4 post-mortem); a 1-thread kernel
// dispatch is ~2 us.
__global__ void zero_counter_kernel(unsigned* __restrict__ counter) {
    *counter = 0u;
}

// ---------------------------------------------------------------------------
// Fused kernel: one block per (b,s) row of V logits.
// Phase 1 (all blocks): chunked online softmax (16 elems/iter via 4 coalesced
//   float4 loads, chunk-max tree + single deferred rescale, first-index
//   argmax), write per-row nll + argmax.
// Phase 2 (last-finishing block only, rocPRIM-style release/acquire via
//   device-scope atomic counter): CE mean + first-EOS / NEXT_LINE scans on
//   L2-hot nll/am + final scalar. Deterministic: fixed reduction orders,
//   finalize reads fixed data regardless of which block runs it.
// ---------------------------------------------------------------------------
__global__ __launch_bounds__(THREADS) void fused_ce_kernel(
    const float* __restrict__ pred, const int* __restrict__ target,
    float* __restrict__ nll_out, int* __restrict__ am_out,
    unsigned* __restrict__ counter, float* __restrict__ out,
    int V, int B, int S)
{
    const int row = blockIdx.x;
    const float* rp = pred + (size_t)row * (size_t)V;
    const int tid = threadIdx.x;
    const int V4 = V >> 2;          // float4 count (8000)
    const int SEG = V4 >> 2;        // float4 per segment (2000), 4 segments
    const int SEG4 = SEG << 2;      // elements per segment (8000)

    const int t = target[row];
    float xt = 0.0f;
    if (tid == 0) xt = rp[t];       // issue early; consumed after the loop

    const vf4* rp4 = (const vf4*)rp;

    float m = -FLT_MAX;
    float s = 0.0f;
    int bi = 0;

    for (int i = tid; i < SEG; i += THREADS) {
        vf4 v0 = __builtin_nontemporal_load(rp4 + i);
        vf4 v1 = __builtin_nontemporal_load(rp4 + i + SEG);
        vf4 v2 = __builtin_nontemporal_load(rp4 + i + 2 * SEG);
        vf4 v3 = __builtin_nontemporal_load(rp4 + i + 3 * SEG);
        float x[16];
#pragma unroll
        for (int c = 0; c < 4; ++c) {
            x[c] = v0[c]; x[4 + c] = v1[c]; x[8 + c] = v2[c]; x[12 + c] = v3[c];
        }
        // chunk max (tree, ILP)
        float m8[8];
#pragma unroll
        for (int j = 0; j < 8; ++j) m8[j] = fmaxf(x[2 * j], x[2 * j + 1]);
        float m4[4];
#pragma unroll
        for (int j = 0; j < 4; ++j) m4[j] = fmaxf(m8[2 * j], m8[2 * j + 1]);
        float mc = fmaxf(fmaxf(m4[0], m4[1]), fmaxf(m4[2], m4[3]));

        // earliest-index element offset of mc within the chunk.
        // slot j holds element (i<<2) + (j>>2)*SEG4 + (j&3); slot order is
        // increasing global index, so scanning j=14..0 keeps the earliest.
        int off = 3 * SEG4 + 3;
#pragma unroll
        for (int j = 14; j >= 0; --j)
            off = (x[j] == mc) ? ((j >> 2) * SEG4 + (j & 3)) : off;
        if (mc > m) bi = (i << 2) + off;   // strict > keeps earliest across chunks

        // deferred-rescale exp sum (all exps independent)
        float nm = fmaxf(m, mc);
        float nms = -nm * LOG2E;
        float r = exp2f(__builtin_fmaf(m, LOG2E, nms)); // m=-FLT_MAX -> 0
#pragma unroll
        for (int j = 0; j < 16; ++j)
            x[j] = exp2f(__builtin_fmaf(x[j], LOG2E, nms));
#pragma unroll
        for (int j = 0; j < 8; ++j) x[j] += x[j + 8];
#pragma unroll
        for (int j = 0; j < 4; ++j) x[j] += x[j + 4];
        float cs = (x[0] + x[1]) + (x[2] + x[3]);
        s = __builtin_fmaf(s, r, cs);
        m = nm;
    }

    // generic scalar tail (empty for V % 16 == 0)
    for (int i = (SEG << 4) + tid; i < V; i += THREADS) {
        float xv = rp[i];
        float nm = fmaxf(m, xv);
        float nms = -nm * LOG2E;
        s = s * exp2f(__builtin_fmaf(m, LOG2E, nms))
          + exp2f(__builtin_fmaf(xv, LOG2E, nms));
        if (xv > m) bi = i;
        m = nm;
    }

    // wave64 reduction
#pragma unroll
    for (int off = 32; off > 0; off >>= 1) {
        float m2 = __shfl_down(m, off);
        float s2 = __shfl_down(s, off);
        int bi2 = __shfl_down(bi, off);
        float nm = fmaxf(m, m2);
        float nms = -nm * LOG2E;
        s = s * exp2f(__builtin_fmaf(m, LOG2E, nms))
          + s2 * exp2f(__builtin_fmaf(m2, LOG2E, nms));
        bool take = (m2 > m) || (m2 == m && bi2 < bi);
        bi = take ? bi2 : bi;
        m = nm;
    }

    __shared__ float sm[THREADS / 64], ss[THREADS / 64];
    __shared__ int sbi[THREADS / 64];
    const int wave = tid >> 6;
    const int lane = tid & 63;
    if (lane == 0) { sm[wave] = m; ss[wave] = s; sbi[wave] = bi; }
    __syncthreads();

    if (tid == 0) {
#pragma unroll
        for (int w = 1; w < THREADS / 64; ++w) {
            float m2 = sm[w], s2 = ss[w];
            int bi2 = sbi[w];
            float nm = fmaxf(m, m2);
            float nms = -nm * LOG2E;
            s = s * exp2f(__builtin_fmaf(m, LOG2E, nms))
              + s2 * exp2f(__builtin_fmaf(m2, LOG2E, nms));
            bool take = (m2 > m) || (m2 == m && bi2 < bi);
            bi = take ? bi2 : bi;
            m = nm;
        }
        const float nll = logf(s) + m - xt;   // -log_softmax[target]
        nll_out[row] = (t != IGNORE_IDX) ? nll : 0.0f;
        am_out[row] = bi;
    }

    // ---- release: make this block's nll/am visible, count completion ----
    __shared__ int is_last;
    if (tid == 0) {
        __threadfence();
        unsigned prev = atomicAdd(counter, 1u);
        is_last = (prev == (unsigned)(gridDim.x - 1));
    }
    __syncthreads();
    if (!is_last) return;
    __threadfence();   // acquire: invalidate stale lines before cross-block reads

    // =================== finalize (last block, 256 threads) ===================
    __shared__ float sfce[THREADS / 64];
    __shared__ int svc[THREADS / 64];
    __shared__ int sfirst[8], scount[8];
    const int BS = B * S;

    // CE numerator + valid count (vectorized, deterministic order)
    float ces = 0.0f;
    int vc = 0;
    const float4* nll4 = (const float4*)nll_out;
    const int4* tg4 = (const int4*)target;
    const int NV = BS >> 2;
    for (int i = tid; i < NV; i += THREADS) {
        float4 v = nll4[i];
        ces += (v.x + v.y) + (v.z + v.w);
        int4 tv = tg4[i];
        vc += (tv.x != IGNORE_IDX) + (tv.y != IGNORE_IDX)
            + (tv.z != IGNORE_IDX) + (tv.w != IGNORE_IDX);
    }
#pragma unroll
    for (int off = 32; off > 0; off >>= 1) {
        ces += __shfl_down(ces, off);
        vc += __shfl_down(vc, off);
    }
    if (lane == 0) { sfce[wave] = ces; svc[wave] = vc; }

    // scans: 8 tasks (4 rows x {argmax,target}) over 4 waves, 2 tasks/wave
    for (int task = wave; task < 2 * B; task += THREADS / 64) {
        const int r = task >> 1;
        const int* ids = (task & 1) ? (target + r * S) : (am_out + r * S);
        const int4* id4 = (const int4*)ids;
        const int S4 = S >> 2;

        int lmin = INT_MAX;
        for (int i = lane; i < S4; i += 64) {
            int4 v = id4[i];
            const int base = i << 2;
            int idx = INT_MAX;
            if (v.w == EOS_ID) idx = base + 3;
            if (v.z == EOS_ID) idx = base + 2;
            if (v.y == EOS_ID) idx = base + 1;
            if (v.x == EOS_ID) idx = base;
            lmin = min(lmin, idx);
        }
#pragma unroll
        for (int off = 32; off > 0; off >>= 1)
            lmin = min(lmin, __shfl_down(lmin, off));
        lmin = __shfl(lmin, 0);
        const int first = min(lmin, S - 1);

        int c = 0;
        for (int i = lane; i < S4; i += 64) {
            int4 v = id4[i];                    // L1-hot second pass
            const int base = i << 2;
            c += (v.x == NEXT_LINE_ID && base <= first);
            c += (v.y == NEXT_LINE_ID && base + 1 <= first);
            c += (v.z == NEXT_LINE_ID && base + 2 <= first);
            c += (v.w == NEXT_LINE_ID && base + 3 <= first);
        }
#pragma unroll
        for (int off = 32; off > 0; off >>= 1)
            c += __shfl_down(c, off);
        if (lane == 0) { sfirst[task] = first; scount[task] = c; }
    }
    __syncthreads();

    if (tid == 0) {
        float ce_total = 0.0f;
        int vtot = 0;
#pragma unroll
        for (int w = 0; w < THREADS / 64; ++w) { ce_total += sfce[w]; vtot += svc[w]; }
        int SL = 0, SC = 0;
#pragma unroll
        for (int b = 0; b < 4; ++b) {
            SL += abs(sfirst[2 * b] - sfirst[2 * b + 1]);
            SC += abs(scount[2 * b] - scount[2 * b + 1]);
        }
        float ce = ce_total / fmaxf((float)vtot, 1.0f);
        out[0] = 0.98f * ce + 0.01f * ((float)SL / (float)B)
                            + 0.01f * ((float)SC / (float)B);
    }
}

extern "C" void kernel_launch(void* const* d_in, const int* in_sizes, int n_in,
                              void* d_out, int out_size, void* d_ws, size_t ws_size,
                              hipStream_t stream)
{
    const float* pred = (const float*)d_in[0];
    const int* target = (const int*)d_in[1];
    float* out = (float*)d_out;

    const int rows = in_sizes[1];                         // B*S = 8192
    const int V = (int)((long long)in_sizes[0] / rows);   // 32000
    const int B = 4;
    const int S = rows / B;                               // 2048

    float* nll = (float*)d_ws;
    int* am = (int*)(nll + rows);
    unsigned* counter = (unsigned*)(am + rows);

    // counter must be 0 at every call (ws is poisoned once, never re-poisoned);
    // use a kernel, NOT hipMemsetAsync (memset graph node = ~400+ us, R4).
    zero_counter_kernel<<<1, 1, 0, stream>>>(counter);

    fused_ce_kernel<<<rows, THREADS, 0, stream>>>(pred, target, nll, am,
                                                  counter, out, V, B, S);
}

// Round 6
// 169.950 us; speedup vs baseline: 3.4382x; 3.4269x over previous
//
#include <hip/hip_runtime.h>
#include <cfloat>
#include <climits>

#define EOS_ID 1
#define NEXT_LINE_ID 2
#define IGNORE_IDX 0

constexpr int THREADS = 256;
constexpr int FTHREADS = 1024;
constexpr float LOG2E = 1.4426950408889634f;

typedef float vf4 __attribute__((ext_vector_type(4)));

// NOTE (R4/R5 post-mortem): do NOT fuse the finalize into the streaming kernel
// via an atomic-counter "last block done" pattern. __threadfence() on gfx950
// is an L2 writeback/invalidate (XCD L2s are not agent-coherent); running it
// in all 8192 blocks cost +415 us. Two kernels, ~5 us tail, is the right shape.

// ---------------------------------------------------------------------------
// Kernel 1: one block per (b,s) row of V logits.
// Chunked online softmax: 16 elements/iter via 4 coalesced float4 loads,
// chunk-max tree + single deferred rescale (17 exps / 16 elems, all parallel),
// argmax with first-index tie-break. Deterministic reduction order.
// ---------------------------------------------------------------------------
__global__ __launch_bounds__(THREADS) void row_pass_kernel(
    const float* __restrict__ pred, const int* __restrict__ target,
    float* __restrict__ nll_out, int* __restrict__ am_out, int V)
{
    const int row = blockIdx.x;
    const float* rp = pred + (size_t)row * (size_t)V;
    const int tid = threadIdx.x;
    const int V4 = V >> 2;          // float4 count (8000)
    const int SEG = V4 >> 2;        // float4 per segment (2000), 4 segments
    const int SEG4 = SEG << 2;      // elements per segment (8000)

    const int t = target[row];
    float xt = 0.0f;
    if (tid == 0) xt = rp[t];       // issue early; consumed after the loop

    const vf4* rp4 = (const vf4*)rp;

    float m = -FLT_MAX;
    float s = 0.0f;
    int bi = 0;

    for (int i = tid; i < SEG; i += THREADS) {
        vf4 v0 = __builtin_nontemporal_load(rp4 + i);
        vf4 v1 = __builtin_nontemporal_load(rp4 + i + SEG);
        vf4 v2 = __builtin_nontemporal_load(rp4 + i + 2 * SEG);
        vf4 v3 = __builtin_nontemporal_load(rp4 + i + 3 * SEG);
        float x[16];
#pragma unroll
        for (int c = 0; c < 4; ++c) {
            x[c] = v0[c]; x[4 + c] = v1[c]; x[8 + c] = v2[c]; x[12 + c] = v3[c];
        }
        // chunk max (tree, ILP)
        float m8[8];
#pragma unroll
        for (int j = 0; j < 8; ++j) m8[j] = fmaxf(x[2 * j], x[2 * j + 1]);
        float m4[4];
#pragma unroll
        for (int j = 0; j < 4; ++j) m4[j] = fmaxf(m8[2 * j], m8[2 * j + 1]);
        float mc = fmaxf(fmaxf(m4[0], m4[1]), fmaxf(m4[2], m4[3]));

        // earliest-index element offset of mc within the chunk.
        // slot j holds element (i<<2) + (j>>2)*SEG4 + (j&3); slot order is
        // increasing global index, so scanning j=14..0 keeps the earliest.
        int off = 3 * SEG4 + 3;
#pragma unroll
        for (int j = 14; j >= 0; --j)
            off = (x[j] == mc) ? ((j >> 2) * SEG4 + (j & 3)) : off;
        if (mc > m) bi = (i << 2) + off;   // strict > keeps earliest across chunks

        // deferred-rescale exp sum (all exps independent)
        float nm = fmaxf(m, mc);
        float nms = -nm * LOG2E;
        float r = exp2f(__builtin_fmaf(m, LOG2E, nms)); // m=-FLT_MAX -> exp2(-inf)=0
#pragma unroll
        for (int j = 0; j < 16; ++j)
            x[j] = exp2f(__builtin_fmaf(x[j], LOG2E, nms));
#pragma unroll
        for (int j = 0; j < 8; ++j) x[j] += x[j + 8];
#pragma unroll
        for (int j = 0; j < 4; ++j) x[j] += x[j + 4];
        float cs = (x[0] + x[1]) + (x[2] + x[3]);
        s = __builtin_fmaf(s, r, cs);
        m = nm;
    }

    // generic scalar tail (empty for V % 16 == 0)
    for (int i = (SEG << 4) + tid; i < V; i += THREADS) {
        float xv = rp[i];
        float nm = fmaxf(m, xv);
        float nms = -nm * LOG2E;
        s = s * exp2f(__builtin_fmaf(m, LOG2E, nms))
          + exp2f(__builtin_fmaf(xv, LOG2E, nms));
        if (xv > m) bi = i;
        m = nm;
    }

    // wave64 reduction
#pragma unroll
    for (int off = 32; off > 0; off >>= 1) {
        float m2 = __shfl_down(m, off);
        float s2 = __shfl_down(s, off);
        int bi2 = __shfl_down(bi, off);
        float nm = fmaxf(m, m2);
        float nms = -nm * LOG2E;
        s = s * exp2f(__builtin_fmaf(m, LOG2E, nms))
          + s2 * exp2f(__builtin_fmaf(m2, LOG2E, nms));
        bool take = (m2 > m) || (m2 == m && bi2 < bi);
        bi = take ? bi2 : bi;
        m = nm;
    }

    __shared__ float sm[THREADS / 64], ss[THREADS / 64];
    __shared__ int sbi[THREADS / 64];
    const int wave = tid >> 6;
    if ((tid & 63) == 0) { sm[wave] = m; ss[wave] = s; sbi[wave] = bi; }
    __syncthreads();

    if (tid == 0) {
#pragma unroll
        for (int w = 1; w < THREADS / 64; ++w) {
            float m2 = sm[w], s2 = ss[w];
            int bi2 = sbi[w];
            float nm = fmaxf(m, m2);
            float nms = -nm * LOG2E;
            s = s * exp2f(__builtin_fmaf(m, LOG2E, nms))
              + s2 * exp2f(__builtin_fmaf(m2, LOG2E, nms));
            bool take = (m2 > m) || (m2 == m && bi2 < bi);
            bi = take ? bi2 : bi;
            m = nm;
        }
        const float nll = logf(s) + m - xt;   // -log_softmax[target]
        nll_out[row] = (t != IGNORE_IDX) ? nll : 0.0f;
        am_out[row] = bi;
    }
}

// ---------------------------------------------------------------------------
// Kernel 2: single 1024-thread block, fully vectorized.
//  - CE sum + valid count: float4/int4 loads, 2 iters/thread, wave shfl reduce.
//  - Scans: 8 wave-tasks (4 rows x {argmax,target}), int4 loads, 8 iters/lane.
//  - One barrier, LDS combine, thread 0 writes the scalar.
// ---------------------------------------------------------------------------
__global__ __launch_bounds__(FTHREADS) void finalize_kernel(
    const float* __restrict__ nll, const int* __restrict__ am,
    const int* __restrict__ target, float* __restrict__ out, int B, int S)
{
    __shared__ float sf[FTHREADS / 64];
    __shared__ int sv[FTHREADS / 64];
    __shared__ int sfirst[8], scount[8];

    const int tid = threadIdx.x;
    const int lane = tid & 63;
    const int wave = tid >> 6;
    const int BS = B * S;

    // ---- CE numerator + valid count (vectorized, deterministic order) ----
    float ces = 0.0f;
    int vc = 0;
    const float4* nll4 = (const float4*)nll;
    const int4* tg4 = (const int4*)target;
    const int NV = BS >> 2;
    for (int i = tid; i < NV; i += FTHREADS) {
        float4 v = nll4[i];
        ces += (v.x + v.y) + (v.z + v.w);
        int4 tv = tg4[i];
        vc += (tv.x != IGNORE_IDX) + (tv.y != IGNORE_IDX)
            + (tv.z != IGNORE_IDX) + (tv.w != IGNORE_IDX);
    }
#pragma unroll
    for (int off = 32; off > 0; off >>= 1) {
        ces += __shfl_down(ces, off);
        vc += __shfl_down(vc, off);
    }
    if (lane == 0) { sf[wave] = ces; sv[wave] = vc; }

    // ---- scans: wave w handles row w>>1, array (w&1 ? target : am) ----
    if (wave < 2 * B) {
        const int row = wave >> 1;
        const int* ids = (wave & 1) ? (target + row * S) : (am + row * S);
        const int4* id4 = (const int4*)ids;
        const int S4 = S >> 2;

        int lmin = INT_MAX;
        for (int i = lane; i < S4; i += 64) {
            int4 v = id4[i];
            const int base = i << 2;
            int idx = INT_MAX;
            if (v.w == EOS_ID) idx = base + 3;
            if (v.z == EOS_ID) idx = base + 2;
            if (v.y == EOS_ID) idx = base + 1;
            if (v.x == EOS_ID) idx = base;
            lmin = min(lmin, idx);
        }
#pragma unroll
        for (int off = 32; off > 0; off >>= 1)
            lmin = min(lmin, __shfl_down(lmin, off));
        lmin = __shfl(lmin, 0);
        const int first = min(lmin, S - 1);

        int c = 0;
        for (int i = lane; i < S4; i += 64) {
            int4 v = id4[i];                    // L1-hot second pass
            const int base = i << 2;
            c += (v.x == NEXT_LINE_ID && base <= first);
            c += (v.y == NEXT_LINE_ID && base + 1 <= first);
            c += (v.z == NEXT_LINE_ID && base + 2 <= first);
            c += (v.w == NEXT_LINE_ID && base + 3 <= first);
        }
#pragma unroll
        for (int off = 32; off > 0; off >>= 1)
            c += __shfl_down(c, off);
        if (lane == 0) { sfirst[wave] = first; scount[wave] = c; }
    }
    __syncthreads();

    if (tid == 0) {
        float ce_total = 0.0f;
        int vtot = 0;
#pragma unroll
        for (int w = 0; w < FTHREADS / 64; ++w) { ce_total += sf[w]; vtot += sv[w]; }
        int SL = 0, SC = 0;
#pragma unroll
        for (int b = 0; b < 4; ++b) {
            SL += abs(sfirst[2 * b] - sfirst[2 * b + 1]);
            SC += abs(scount[2 * b] - scount[2 * b + 1]);
        }
        float ce = ce_total / fmaxf((float)vtot, 1.0f);
        out[0] = 0.98f * ce + 0.01f * ((float)SL / (float)B)
                            + 0.01f * ((float)SC / (float)B);
    }
}

extern "C" void kernel_launch(void* const* d_in, const int* in_sizes, int n_in,
                              void* d_out, int out_size, void* d_ws, size_t ws_size,
                              hipStream_t stream)
{
    const float* pred = (const float*)d_in[0];
    const int* target = (const int*)d_in[1];
    float* out = (float*)d_out;

    const int rows = in_sizes[1];                         // B*S = 8192
    const int V = (int)((long long)in_sizes[0] / rows);   // 32000
    const int B = 4;
    const int S = rows / B;                               // 2048

    float* nll = (float*)d_ws;
    int* am = (int*)(nll + rows);

    row_pass_kernel<<<rows, THREADS, 0, stream>>>(pred, target, nll, am, V);
    finalize_kernel<<<1, FTHREADS, 0, stream>>>(nll, am, target, out, B, S);
}